// Round 15
// baseline (1290.930 us; speedup 1.0000x reference)
//
#include <hip/hip_runtime.h>
#include <hip/hip_bf16.h>

// ---------------------------------------------------------------------------
// Encoder: B=4, S=2048, V=32000, D=512, F=2048, L=6, H=8, Dh=64
// fp32 on the wire; bf16 MFMA GEMMs, fp32 residual master.
// ---------------------------------------------------------------------------

typedef unsigned short u16;
typedef __bf16 bf16x8 __attribute__((ext_vector_type(8)));
typedef float f32x4 __attribute__((ext_vector_type(4)));
typedef unsigned short u16x8 __attribute__((ext_vector_type(8)));
typedef unsigned short u16x4 __attribute__((ext_vector_type(4)));

#define S_LEN 2048
#define DM 512
#define FF 2048
#define NHEAD 8
#define QKV_STRIDE 1536

__device__ __forceinline__ u16 f2b(float f) {
    __hip_bfloat16 h = __float2bfloat16(f);   // RNE
    return __builtin_bit_cast(unsigned short, h);
}

typedef const __attribute__((address_space(1))) unsigned int glb_u32;
typedef __attribute__((address_space(3))) unsigned int lds_u32;

__device__ __forceinline__ void async16(const u16* g, u16* l) {
    __builtin_amdgcn_global_load_lds((glb_u32*)g, (lds_u32*)l, 16, 0, 0);
}

// T1: XCD-chunked block swizzle (R12: -107us). HW round-robins linear block
// id over the 8 XCD L2s; remap so each XCD owns a CONTIGUOUS chunk of the
// grid (contiguous M-panels -> A-panel reuse inside one 4MB XCD L2 instead
// of 8x replication). Requires total blocks % 8 == 0.
__device__ __forceinline__ void xcd_swizzle(int& bx, int& by) {
    int gx = gridDim.x;
    int l = blockIdx.y * gx + blockIdx.x;
    int q = (gx * gridDim.y) >> 3;
    int cv = (l & 7) * q + (l >> 3);
    bx = cv % gx;
    by = cv / gx;
}

// ---------------------------------------------------------------------------
// Transpose+convert: Wt[n][k] (bf16) = W[k][n] (fp32), per layer.
// ---------------------------------------------------------------------------
__global__ __launch_bounds__(256) void transp_kernel(
    const float* __restrict__ W, u16* __restrict__ Wt,
    int K, int N, size_t layerStride, int rowOff)
{
    __shared__ float tile[64][65];
    int l = blockIdx.z;
    const float* src = W + (size_t)l * K * N;
    u16* dst = Wt + (size_t)l * layerStride;
    int k0 = blockIdx.y * 64, n0 = blockIdx.x * 64;
    int tid = threadIdx.x;

#pragma unroll
    for (int i = 0; i < 4; i++) {
        int r = (tid >> 4) + i * 16;
        int c4 = (tid & 15) * 4;
        float4 v = *(const float4*)&src[(size_t)(k0 + r) * N + n0 + c4];
        tile[r][c4 + 0] = v.x; tile[r][c4 + 1] = v.y;
        tile[r][c4 + 2] = v.z; tile[r][c4 + 3] = v.w;
    }
    __syncthreads();
#pragma unroll
    for (int it = 0; it < 2; it++) {
        int idx = it * 256 + tid;
        int n = idx >> 3, seg = (idx & 7) * 8;
        u16x8 o;
#pragma unroll
        for (int t = 0; t < 8; t++) o[t] = f2b(tile[seg + t][n]);
        *(u16x8*)&dst[(size_t)(rowOff + n0 + n) * K + k0 + seg] = o;
    }
}

// ---------------------------------------------------------------------------
// Embedding gather: fp32 master + bf16 shadow. One wave per row.
// ---------------------------------------------------------------------------
__global__ __launch_bounds__(256) void embed_kernel(
    const int* __restrict__ src, const float* __restrict__ emb,
    float* __restrict__ xf, u16* __restrict__ xb)
{
    int tid = threadIdx.x, lane = tid & 63, w = tid >> 6;
    int row = blockIdx.x * 4 + w;
    int id = src[row];
    const float* e = emb + (size_t)id * DM + lane * 8;
    float* xo = xf + (size_t)row * DM + lane * 8;
    u16x8 ob;
#pragma unroll
    for (int j = 0; j < 8; j++) {
        float v = e[j];
        xo[j] = v;
        ob[j] = f2b(v);
    }
    *(u16x8*)(xb + (size_t)row * DM + lane * 8) = ob;
}

// ---------------------------------------------------------------------------
// GEMM (wide): C[M,N] = act(A[M,K] @ Bt[N,K]^T + bias)
// 128x128 tile / 256 thr, BK=64, single-buffer (R5 best config) + T1 swizzle.
// T2 XOR-swizzle, both-sides-or-neither. QKV + FF1 only (>=768 blocks).
// ---------------------------------------------------------------------------
template <int ACT, bool OUT_F32>
__global__ __launch_bounds__(256) void gemm_kernel(
    const u16* __restrict__ A, const u16* __restrict__ Bt,
    const float* __restrict__ bias0, const float* __restrict__ bias1,
    const float* __restrict__ bias2, const float* __restrict__ bias3,
    void* __restrict__ Cv, int N, int K)
{
    __shared__ __align__(16) u16 As[128 * 64];
    __shared__ __align__(16) u16 Bs[128 * 64];

    int tid = threadIdx.x, lane = tid & 63, w = tid >> 6;
    int bx, by;
    xcd_swizzle(bx, by);
    int m0 = by * 128, n0 = bx * 128;
    int wm = (w >> 1) * 64, wn = (w & 1) * 64;
    int mi = lane & 15, quad = lane >> 4;
    int sw = mi & 7;                // read-side swizzle key

    f32x4 acc[4][4];
#pragma unroll
    for (int i = 0; i < 4; i++)
#pragma unroll
        for (int j = 0; j < 4; j++) acc[i][j] = (f32x4){0.f, 0.f, 0.f, 0.f};

    // staging geometry: round r covers rows r*32 + (tid>>3), 8x16B blocks/row
    int rr = tid >> 3;                              // 0..31
    int csrc = ((tid & 7) ^ (rr & 7)) * 8;          // swizzled source col (u16)
    int cdst = (tid & 7) * 8;                       // linear LDS col (u16)

    const u16* Asrc[4];
    u16* Adst[4];
#pragma unroll
    for (int r = 0; r < 4; r++) {
        Asrc[r] = A + (size_t)(m0 + r * 32 + rr) * K + csrc;
        Adst[r] = As + (r * 32 + rr) * 64 + cdst;
    }
    const u16* Bsrc[4];
    u16* Bdst[4];
#pragma unroll
    for (int r = 0; r < 4; r++) {
        Bsrc[r] = Bt + (size_t)(n0 + r * 32 + rr) * K + csrc;
        Bdst[r] = Bs + (r * 32 + rr) * 64 + cdst;
    }

    for (int kc = 0; kc < K; kc += 64) {
        __syncthreads();
#pragma unroll
        for (int r = 0; r < 4; r++) async16(Asrc[r] + kc, Adst[r]);
#pragma unroll
        for (int r = 0; r < 4; r++) async16(Bsrc[r] + kc, Bdst[r]);
        __syncthreads();

#pragma unroll
        for (int kk = 0; kk < 2; kk++) {
            int cb = ((kk * 4 + quad) ^ sw) * 8;    // swizzled read col
            bf16x8 af[4], bfr[4];
#pragma unroll
            for (int i = 0; i < 4; i++)
                af[i] = *(const bf16x8*)&As[(wm + i * 16 + mi) * 64 + cb];
#pragma unroll
            for (int j = 0; j < 4; j++)
                bfr[j] = *(const bf16x8*)&Bs[(wn + j * 16 + mi) * 64 + cb];
#pragma unroll
            for (int i = 0; i < 4; i++)
#pragma unroll
                for (int j = 0; j < 4; j++)
                    acc[i][j] = __builtin_amdgcn_mfma_f32_16x16x32_bf16(
                        af[i], bfr[j], acc[i][j], 0, 0, 0);
        }
    }

#pragma unroll
    for (int j = 0; j < 4; j++) {
        int col = n0 + wn + j * 16 + mi;
        int bi = col >> 9;
        const float* bp = (bi == 0) ? bias0 : (bi == 1) ? bias1
                        : (bi == 2) ? bias2 : bias3;
        float bb = bp[col & 511];
#pragma unroll
        for (int i = 0; i < 4; i++) {
#pragma unroll
            for (int r = 0; r < 4; r++) {
                int row = m0 + wm + i * 16 + quad * 4 + r;
                float o = acc[i][j][r] + bb;
                if (ACT) o = fmaxf(o, 0.f);
                if (OUT_F32) ((float*)Cv)[(size_t)row * N + col] = o;
                else         ((u16*)Cv)[(size_t)row * N + col] = f2b(o);
            }
        }
    }
}

// ---------------------------------------------------------------------------
// GEMM (narrow-N, N=512): 64x64 tile / 256 thr, BK=64, 2-phase dbuf + T1.
// grid 1024 blocks -> 4 blk/CU. Used for AO (K=512) AND FF2 (K=2048) -- the
// R12 best routing (R13/R14 alternatives were neutral or worse).
// ADD_RES: fuse the residual add (o += Res[row][col], AFTER activation,
// matching LN(x + relu(...))) so dlt holds the pre-LN sum and the LN kernel
// reads ONE array instead of two (144 -> 80 MB per LN dispatch).
// ---------------------------------------------------------------------------
template <int ACT, bool ADD_RES>
__global__ __launch_bounds__(256) void gemm64_kernel(
    const u16* __restrict__ A, const u16* __restrict__ Bt,
    const float* __restrict__ bias0, const float* __restrict__ Res,
    float* __restrict__ Cv, int N, int K)
{
    __shared__ __align__(16) u16 As[2][64 * 64];
    __shared__ __align__(16) u16 Bs[2][64 * 64];

    int tid = threadIdx.x, lane = tid & 63, w = tid >> 6;
    int bx, by;
    xcd_swizzle(bx, by);
    int m0 = by * 64, n0 = bx * 64;
    int wm = (w >> 1) * 32, wn = (w & 1) * 32;
    int mi = lane & 15, quad = lane >> 4;
    int sw = mi & 7;

    f32x4 acc[2][2];
#pragma unroll
    for (int i = 0; i < 2; i++)
#pragma unroll
        for (int j = 0; j < 2; j++) acc[i][j] = (f32x4){0.f, 0.f, 0.f, 0.f};

    int rr = tid >> 3;                              // 0..31
    int csrc = ((tid & 7) ^ (rr & 7)) * 8;          // swizzled source col
    int cdst = (tid & 7) * 8;                       // linear LDS col

    const u16* Asrc[2];
    int Aoff[2];
#pragma unroll
    for (int r = 0; r < 2; r++) {
        Asrc[r] = A + (size_t)(m0 + r * 32 + rr) * K + csrc;
        Aoff[r] = (r * 32 + rr) * 64 + cdst;
    }
    const u16* Bsrc[2];
    int Boff[2];
#pragma unroll
    for (int r = 0; r < 2; r++) {
        Bsrc[r] = Bt + (size_t)(n0 + r * 32 + rr) * K + csrc;
        Boff[r] = (r * 32 + rr) * 64 + cdst;
    }

    // prologue: stage tile 0 into buffer 0
#pragma unroll
    for (int r = 0; r < 2; r++) async16(Asrc[r], &As[0][Aoff[r]]);
#pragma unroll
    for (int r = 0; r < 2; r++) async16(Bsrc[r], &Bs[0][Boff[r]]);
    __syncthreads();

    int cur = 0;
    for (int kc = 0; kc < K; kc += 64) {
        int nxt = kc + 64;
        if (nxt < K) {
#pragma unroll
            for (int r = 0; r < 2; r++) async16(Asrc[r] + nxt, &As[cur ^ 1][Aoff[r]]);
#pragma unroll
            for (int r = 0; r < 2; r++) async16(Bsrc[r] + nxt, &Bs[cur ^ 1][Boff[r]]);
        }

#pragma unroll
        for (int kk = 0; kk < 2; kk++) {
            int cb = ((kk * 4 + quad) ^ sw) * 8;
            bf16x8 af[2], bfr[2];
#pragma unroll
            for (int i = 0; i < 2; i++)
                af[i] = *(const bf16x8*)&As[cur][(wm + i * 16 + mi) * 64 + cb];
#pragma unroll
            for (int j = 0; j < 2; j++)
                bfr[j] = *(const bf16x8*)&Bs[cur][(wn + j * 16 + mi) * 64 + cb];
#pragma unroll
            for (int i = 0; i < 2; i++)
#pragma unroll
                for (int j = 0; j < 2; j++)
                    acc[i][j] = __builtin_amdgcn_mfma_f32_16x16x32_bf16(
                        af[i], bfr[j], acc[i][j], 0, 0, 0);
        }

        __syncthreads();        // drains next-tile loads; protects buf reuse
        cur ^= 1;
    }

#pragma unroll
    for (int j = 0; j < 2; j++) {
        int col = n0 + wn + j * 16 + mi;
        float bb = bias0[col & 511];
#pragma unroll
        for (int i = 0; i < 2; i++) {
#pragma unroll
            for (int r = 0; r < 4; r++) {
                int row = m0 + wm + i * 16 + quad * 4 + r;
                float o = acc[i][j][r] + bb;
                if (ACT) o = fmaxf(o, 0.f);
                if (ADD_RES) o += Res[(size_t)row * N + col];
                Cv[(size_t)row * N + col] = o;
            }
        }
    }
}

// ---------------------------------------------------------------------------
// Flash attention (causal), fused-QKV input.  (R8 version, session-best.)
// ONE 64-row q-tile per block; 1024 blocks; CU-stack-balancing swizzle;
// two-deep K/V register prefetch. Swapped QK^T + in-register softmax +
// defer-rescale. R9-R11 established the structure is at its floor.
// ---------------------------------------------------------------------------
__global__ __launch_bounds__(256) void attn_kernel(
    const u16* __restrict__ qkv, u16* __restrict__ O)
{
    __shared__ __align__(16) u16 Kl[64][72];
    __shared__ __align__(16) u16 Vt[64][72];
    __shared__ __align__(16) u16 Pl[4][16][72];

    int tid = threadIdx.x, lane = tid & 63, w = tid >> 6;
    int id = blockIdx.x;          // 0..1023
    int u = id & 255, v = id >> 8;
    int p = u & 15;
    int qt = (v & 1) ? (31 - p) : p;
    int bh = (u >> 4) | ((v >> 1) << 4);
    int b = bh >> 3, h = bh & 7;
    int mi = lane & 15, quad = lane >> 4, k8 = quad * 8;

    size_t qbase = ((size_t)b * S_LEN) * QKV_STRIDE + h * 64;
    const u16* Qp = qkv + qbase;
    const u16* Kp = qkv + qbase + 512;
    const u16* Vp = qkv + qbase + 1024;
    size_t obase = ((size_t)b * S_LEN) * DM + h * 64;

    int srow = tid >> 2, sseg = tid & 3;
    int vcol = srow ^ (sseg * 8);

    f32x4 zero4 = {0.f, 0.f, 0.f, 0.f};
    const float SCL = 0.125f * 1.44269504089f;   // 1/sqrt(64) * log2(e)

    int q0 = qt * 64;

    // Q fragments (B-operand of the swapped QK^T): row = mi
    const u16* qrow = Qp + (size_t)(q0 + w * 16 + mi) * QKV_STRIDE;
    bf16x8 bq0 = *(const bf16x8*)(qrow + k8);
    bf16x8 bq1 = *(const bf16x8*)(qrow + 32 + k8);

    // two-deep prefetch: tiles 0 (a-regs) and 1 (b-regs). Tile-1 rows
    // 64..127 are always in-bounds; refills guarded by kt+2 <= qt.
    const u16* kr = Kp + (size_t)srow * QKV_STRIDE + sseg * 16;
    const u16* vr = Vp + (size_t)srow * QKV_STRIDE + sseg * 16;
    const size_t TSTR = (size_t)64 * QKV_STRIDE;
    u16x8 ka0 = *(const u16x8*)kr,          ka1 = *(const u16x8*)(kr + 8);
    u16x8 va0 = *(const u16x8*)vr,          va1 = *(const u16x8*)(vr + 8);
    u16x8 kb0 = *(const u16x8*)(kr + TSTR), kb1 = *(const u16x8*)(kr + TSTR + 8);
    u16x8 vb0 = *(const u16x8*)(vr + TSTR), vb1 = *(const u16x8*)(vr + TSTR + 8);

    // per-lane softmax state for q = w*16 + mi (replicated across quads)
    float mst = -__builtin_inff();
    float lst = 0.f;
    f32x4 acc[4];    // acc[g2][r] = O[q=quad*4+r][d=g2*16+mi]
#pragma unroll
    for (int g = 0; g < 4; g++) acc[g] = zero4;

    auto compute_tile = [&](int kt) {
        // QK^T (swapped): sc[g][r] = S[q = w*16+mi][k = g*16+quad*4+r] * SCL
        f32x4 sc[4];
#pragma unroll
        for (int g = 0; g < 4; g++) {
            bf16x8 a0 = *(const bf16x8*)&Kl[g * 16 + mi][k8];
            bf16x8 a1 = *(const bf16x8*)&Kl[g * 16 + mi][32 + k8];
            f32x4 s = __builtin_amdgcn_mfma_f32_16x16x32_bf16(a0, bq0, zero4, 0, 0, 0);
            s = __builtin_amdgcn_mfma_f32_16x16x32_bf16(a1, bq1, s, 0, 0, 0);
            sc[g] = s * SCL;
        }

        if (kt == qt) {   // causal mask on diagonal tile: k_local > q_local
            int qloc = w * 16 + mi;
#pragma unroll
            for (int g = 0; g < 4; g++) {
#pragma unroll
                for (int r = 0; r < 4; r++)
                    if (g * 16 + quad * 4 + r > qloc) sc[g][r] = -1e30f;
            }
        }

        // row max: in-register tree over 16 + 2-step cross-quad shfl
        f32x4 m4 = sc[0];
#pragma unroll
        for (int g = 1; g < 4; g++)
#pragma unroll
            for (int r = 0; r < 4; r++) m4[r] = fmaxf(m4[r], sc[g][r]);
        float rm = fmaxf(fmaxf(m4[0], m4[1]), fmaxf(m4[2], m4[3]));
        rm = fmaxf(rm, __shfl_xor(rm, 16));
        rm = fmaxf(rm, __shfl_xor(rm, 32));

        bool nore = __all(rm <= mst);        // wave-uniform: max didn't grow
        float mnew = fmaxf(mst, rm);

        float pr[4][4];
        f32x4 ps = zero4;
#pragma unroll
        for (int g = 0; g < 4; g++)
#pragma unroll
            for (int r = 0; r < 4; r++) {
                float p2 = exp2f(sc[g][r] - mnew);
                pr[g][r] = p2;
                ps[r] += p2;
            }
        float rs = (ps[0] + ps[1]) + (ps[2] + ps[3]);
        rs += __shfl_xor(rs, 16);
        rs += __shfl_xor(rs, 32);

        if (!nore) {
            float alpha = exp2f(mst - mnew);
            mst = mnew;
            lst *= alpha;
            // redistribute alpha to acc rows (q-local = quad*4+r)
            float aR[4];
#pragma unroll
            for (int r = 0; r < 4; r++) aR[r] = __shfl(alpha, quad * 4 + r);
#pragma unroll
            for (int g2 = 0; g2 < 4; g2++)
#pragma unroll
                for (int r = 0; r < 4; r++) acc[g2][r] *= aR[r];
        }
        lst += rs;

        // P -> LDS (wave-private): row = q = mi, cols g*16+quad*4..+3
#pragma unroll
        for (int g = 0; g < 4; g++) {
            u16x4 pk;
#pragma unroll
            for (int r = 0; r < 4; r++) pk[r] = f2b(pr[g][r]);
            *(u16x4*)&Pl[w][mi][g * 16 + quad * 4] = pk;
        }

        // PV (Vt read with un-swizzle)
#pragma unroll
        for (int kc2 = 0; kc2 < 2; kc2++) {
            bf16x8 ap = *(const bf16x8*)&Pl[w][mi][kc2 * 32 + k8];
#pragma unroll
            for (int g2 = 0; g2 < 4; g2++) {
                bf16x8 bv = *(const bf16x8*)&Vt[g2 * 16 + mi][kc2 * 32 + ((quad ^ g2) * 8)];
                acc[g2] = __builtin_amdgcn_mfma_f32_16x16x32_bf16(ap, bv, acc[g2], 0, 0, 0);
            }
        }
    };

#define ATTN_STEP(KT, K0, K1, V0, V1)                                        \
    {                                                                        \
        const int kt_ = (KT);                                                \
        __syncthreads();                                                     \
        *(u16x8*)&Kl[srow][sseg * 16] = K0;                                  \
        *(u16x8*)&Kl[srow][sseg * 16 + 8] = K1;                              \
        _Pragma("unroll")                                                    \
        for (int j = 0; j < 8; j++) {                                        \
            Vt[sseg * 16 + j][vcol] = V0[j];                                 \
            Vt[sseg * 16 + 8 + j][vcol] = V1[j];                             \
        }                                                                    \
        __syncthreads();                                                     \
        if (kt_ + 2 <= qt) {                                                 \
            const u16* krn = kr + (size_t)(kt_ + 2) * TSTR;                  \
            const u16* vrn = vr + (size_t)(kt_ + 2) * TSTR;                  \
            K0 = *(const u16x8*)krn; K1 = *(const u16x8*)(krn + 8);          \
            V0 = *(const u16x8*)vrn; V1 = *(const u16x8*)(vrn + 8);          \
        }                                                                    \
        compute_tile(kt_);                                                   \
    }

    for (int kt = 0; kt <= qt; kt += 2) {
        ATTN_STEP(kt, ka0, ka1, va0, va1);
        if (kt + 1 <= qt) ATTN_STEP(kt + 1, kb0, kb1, vb0, vb1);
    }
#undef ATTN_STEP

    // epilogue: pull l for acc rows (q-local = quad*4+r) via shfl
    float invL[4];
#pragma unroll
    for (int r = 0; r < 4; r++) invL[r] = 1.f / __shfl(lst, quad * 4 + r);
#pragma unroll
    for (int g2 = 0; g2 < 4; g2++)
#pragma unroll
        for (int r = 0; r < 4; r++) {
            float o = acc[g2][r] * invL[r];
            O[obase + (size_t)(q0 + w * 16 + quad * 4 + r) * DM + g2 * 16 + mi] = f2b(o);
        }
}

// ---------------------------------------------------------------------------
// x = LN(sum); sum already holds residual+delta (fused into GEMM epilogue).
// Writes fp32 master + bf16 shadow. One wave per row; float4-vectorized.
// ---------------------------------------------------------------------------
__global__ __launch_bounds__(256) void ln_kernel(
    const float* __restrict__ S, const float* __restrict__ G,
    const float* __restrict__ Bb,
    float* __restrict__ Xout, u16* __restrict__ Bout)
{
    int tid = threadIdx.x, lane = tid & 63, w = tid >> 6;
    int row = blockIdx.x * 4 + w;
    size_t off = (size_t)row * DM + lane * 8;

    float4 a = *(const float4*)&S[off];
    float4 bq = *(const float4*)&S[off + 4];
    float v[8] = {a.x, a.y, a.z, a.w, bq.x, bq.y, bq.z, bq.w};

    float s = 0.f;
#pragma unroll
    for (int j = 0; j < 8; j++) s += v[j];
#pragma unroll
    for (int d = 1; d < 64; d <<= 1) s += __shfl_xor(s, d);
    float mean = s * (1.f / 512.f);
    float vs = 0.f;
#pragma unroll
    for (int j = 0; j < 8; j++) { float t = v[j] - mean; vs += t * t; }
#pragma unroll
    for (int d = 1; d < 64; d <<= 1) vs += __shfl_xor(vs, d);
    float rstd = rsqrtf(vs * (1.f / 512.f) + 1e-5f);

    float4 g0 = *(const float4*)&G[lane * 8];
    float4 g1 = *(const float4*)&G[lane * 8 + 4];
    float4 b0 = *(const float4*)&Bb[lane * 8];
    float4 b1 = *(const float4*)&Bb[lane * 8 + 4];
    float gg[8] = {g0.x, g0.y, g0.z, g0.w, g1.x, g1.y, g1.z, g1.w};
    float bb[8] = {b0.x, b0.y, b0.z, b0.w, b1.x, b1.y, b1.z, b1.w};

    float o[8];
    u16x8 ob;
#pragma unroll
    for (int j = 0; j < 8; j++) {
        o[j] = (v[j] - mean) * rstd * gg[j] + bb[j];
        ob[j] = f2b(o[j]);
    }
    *(float4*)&Xout[off]     = (float4){o[0], o[1], o[2], o[3]};
    *(float4*)&Xout[off + 4] = (float4){o[4], o[5], o[6], o[7]};
    *(u16x8*)&Bout[off] = ob;
}

// ---------------------------------------------------------------------------
extern "C" void kernel_launch(void* const* d_in, const int* in_sizes, int n_in,
                              void* d_out, int out_size, void* d_ws, size_t ws_size,
                              hipStream_t stream)
{
    const int*   src  = (const int*)d_in[0];
    const float* emb  = (const float*)d_in[1];
    const float* ln_g = (const float*)d_in[2];
    const float* ln_b = (const float*)d_in[3];
    const float* wq = (const float*)d_in[4];
    const float* bq = (const float*)d_in[5];
    const float* wk = (const float*)d_in[6];
    const float* bk = (const float*)d_in[7];
    const float* wv = (const float*)d_in[8];
    const float* bv = (const float*)d_in[9];
    const float* wo = (const float*)d_in[10];
    const float* bo = (const float*)d_in[11];
    const float* w1 = (const float*)d_in[12];
    const float* b1 = (const float*)d_in[13];
    const float* w2 = (const float*)d_in[14];
    const float* b2 = (const float*)d_in[15];

    char* ws = (char*)d_ws;
    float* xf  = (float*)(ws);
    u16*   xb  = (u16*)(ws + (16u << 20));
    u16*   qkv = (u16*)(ws + (24u << 20));
    u16*   ab  = (u16*)(ws + (48u << 20));
    u16*   h1  = (u16*)(ws + (24u << 20));   // aliases qkv+ab
    float* dlt = (float*)(ws + (56u << 20));
    u16*   wbf = (u16*)(ws + (72u << 20));

    u16* qkvt = wbf;                              // [L][1536][512]
    u16* wot  = wbf + 6u * 1536 * 512;            // [L][512][512]
    u16* w1t  = wot + 6u * 512 * 512;             // [L][2048][512]
    u16* w2t  = w1t + 6u * 512 * 2048;            // [L][512][2048]

    const int ROWS = 4 * S_LEN;   // 8192

    transp_kernel<<<dim3(8, 8, 6),  256, 0, stream>>>(wq, qkvt, 512, 512, 1536u * 512, 0);
    transp_kernel<<<dim3(8, 8, 6),  256, 0, stream>>>(wk, qkvt, 512, 512, 1536u * 512, 512);
    transp_kernel<<<dim3(8, 8, 6),  256, 0, stream>>>(wv, qkvt, 512, 512, 1536u * 512, 1024);
    transp_kernel<<<dim3(8, 8, 6),  256, 0, stream>>>(wo, wot, 512, 512, 512u * 512, 0);
    transp_kernel<<<dim3(32, 8, 6), 256, 0, stream>>>(w1, w1t, 512, 2048, 2048u * 512, 0);
    transp_kernel<<<dim3(8, 32, 6), 256, 0, stream>>>(w2, w2t, 2048, 512, 512u * 2048, 0);

    embed_kernel<<<ROWS / 4, 256, 0, stream>>>(src, emb, xf, xb);

    dim3 gqkv(1536 / 128, ROWS / 128);   // 768 blocks (div by 8)
    dim3 g64(512 / 64, ROWS / 64);       // 1024 blocks (div by 8)
    dim3 g2048(2048 / 128, ROWS / 128);  // 1024 blocks (div by 8)

    for (int l = 0; l < 6; l++) {
        const u16* Wqkv = qkvt + (size_t)l * 1536 * 512;
        const u16* Wo   = wot + (size_t)l * 512 * 512;
        const u16* W1   = w1t + (size_t)l * 2048 * 512;
        const u16* W2   = w2t + (size_t)l * 512 * 2048;
        const float* Bq = bq + l * DM;
        const float* Bk = bk + l * DM;
        const float* Bv = bv + l * DM;
        const float* Bo = bo + l * DM;
        const float* B1 = b1 + l * FF;
        const float* B2 = b2 + l * DM;

        gemm_kernel<0, false><<<gqkv, 256, 0, stream>>>(
            xb, Wqkv, Bq, Bk, Bv, Bv, qkv, QKV_STRIDE, 512);

        attn_kernel<<<1024, 256, 0, stream>>>(qkv, ab);

        gemm64_kernel<0, true><<<g64, 256, 0, stream>>>(
            ab, Wo, Bo, xf, dlt, 512, 512);
        ln_kernel<<<ROWS / 4, 256, 0, stream>>>(dlt, ln_g, ln_b, xf, xb);

        gemm_kernel<1, false><<<g2048, 256, 0, stream>>>(
            xb, W1, B1, B1 + 512, B1 + 1024, B1 + 1536, h1, FF, 512);
        gemm64_kernel<1, true><<<g64, 256, 0, stream>>>(
            h1, W2, B2, xf, dlt, 512, 2048);
        ln_kernel<<<ROWS / 4, 256, 0, stream>>>(dlt, ln_g, ln_b,
                                                (l == 5) ? (float*)d_out : xf, xb);
    }
}

// Round 16
// 1172.413 us; speedup vs baseline: 1.1011x; 1.1011x over previous
//
#include <hip/hip_runtime.h>
#include <hip/hip_bf16.h>

// ---------------------------------------------------------------------------
// Encoder: B=4, S=2048, V=32000, D=512, F=2048, L=6, H=8, Dh=64
// fp32 on the wire; bf16 MFMA GEMMs, fp32 residual master.
// R16 = R12 config (session best, 1175us) + vectorized add_ln.
// ---------------------------------------------------------------------------

typedef unsigned short u16;
typedef __bf16 bf16x8 __attribute__((ext_vector_type(8)));
typedef float f32x4 __attribute__((ext_vector_type(4)));
typedef unsigned short u16x8 __attribute__((ext_vector_type(8)));
typedef unsigned short u16x4 __attribute__((ext_vector_type(4)));

#define S_LEN 2048
#define DM 512
#define FF 2048
#define NHEAD 8
#define QKV_STRIDE 1536

__device__ __forceinline__ u16 f2b(float f) {
    __hip_bfloat16 h = __float2bfloat16(f);   // RNE
    return __builtin_bit_cast(unsigned short, h);
}

typedef const __attribute__((address_space(1))) unsigned int glb_u32;
typedef __attribute__((address_space(3))) unsigned int lds_u32;

__device__ __forceinline__ void async16(const u16* g, u16* l) {
    __builtin_amdgcn_global_load_lds((glb_u32*)g, (lds_u32*)l, 16, 0, 0);
}

// T1: XCD-chunked block swizzle (R12: -107us). HW round-robins linear block
// id over the 8 XCD L2s; remap so each XCD owns a CONTIGUOUS chunk of the
// grid (contiguous M-panels -> A-panel reuse inside one 4MB XCD L2 instead
// of 8x replication). Requires total blocks % 8 == 0.
__device__ __forceinline__ void xcd_swizzle(int& bx, int& by) {
    int gx = gridDim.x;
    int l = blockIdx.y * gx + blockIdx.x;
    int q = (gx * gridDim.y) >> 3;
    int cv = (l & 7) * q + (l >> 3);
    bx = cv % gx;
    by = cv / gx;
}

// ---------------------------------------------------------------------------
// Transpose+convert: Wt[n][k] (bf16) = W[k][n] (fp32), per layer.
// ---------------------------------------------------------------------------
__global__ __launch_bounds__(256) void transp_kernel(
    const float* __restrict__ W, u16* __restrict__ Wt,
    int K, int N, size_t layerStride, int rowOff)
{
    __shared__ float tile[64][65];
    int l = blockIdx.z;
    const float* src = W + (size_t)l * K * N;
    u16* dst = Wt + (size_t)l * layerStride;
    int k0 = blockIdx.y * 64, n0 = blockIdx.x * 64;
    int tid = threadIdx.x;

#pragma unroll
    for (int i = 0; i < 4; i++) {
        int r = (tid >> 4) + i * 16;
        int c4 = (tid & 15) * 4;
        float4 v = *(const float4*)&src[(size_t)(k0 + r) * N + n0 + c4];
        tile[r][c4 + 0] = v.x; tile[r][c4 + 1] = v.y;
        tile[r][c4 + 2] = v.z; tile[r][c4 + 3] = v.w;
    }
    __syncthreads();
#pragma unroll
    for (int it = 0; it < 2; it++) {
        int idx = it * 256 + tid;
        int n = idx >> 3, seg = (idx & 7) * 8;
        u16x8 o;
#pragma unroll
        for (int t = 0; t < 8; t++) o[t] = f2b(tile[seg + t][n]);
        *(u16x8*)&dst[(size_t)(rowOff + n0 + n) * K + k0 + seg] = o;
    }
}

// ---------------------------------------------------------------------------
// Embedding gather: fp32 master + bf16 shadow. One wave per row.
// ---------------------------------------------------------------------------
__global__ __launch_bounds__(256) void embed_kernel(
    const int* __restrict__ src, const float* __restrict__ emb,
    float* __restrict__ xf, u16* __restrict__ xb)
{
    int tid = threadIdx.x, lane = tid & 63, w = tid >> 6;
    int row = blockIdx.x * 4 + w;
    int id = src[row];
    const float* e = emb + (size_t)id * DM + lane * 8;
    float* xo = xf + (size_t)row * DM + lane * 8;
    u16x8 ob;
#pragma unroll
    for (int j = 0; j < 8; j++) {
        float v = e[j];
        xo[j] = v;
        ob[j] = f2b(v);
    }
    *(u16x8*)(xb + (size_t)row * DM + lane * 8) = ob;
}

// ---------------------------------------------------------------------------
// GEMM (wide): C[M,N] = act(A[M,K] @ Bt[N,K]^T + bias)
// 128x128 tile / 256 thr, BK=64, single-buffer (R5 best config) + T1 swizzle.
// T2 XOR-swizzle, both-sides-or-neither. QKV + FF1 only (>=768 blocks).
// ---------------------------------------------------------------------------
template <int ACT, bool OUT_F32>
__global__ __launch_bounds__(256) void gemm_kernel(
    const u16* __restrict__ A, const u16* __restrict__ Bt,
    const float* __restrict__ bias0, const float* __restrict__ bias1,
    const float* __restrict__ bias2, const float* __restrict__ bias3,
    void* __restrict__ Cv, int N, int K)
{
    __shared__ __align__(16) u16 As[128 * 64];
    __shared__ __align__(16) u16 Bs[128 * 64];

    int tid = threadIdx.x, lane = tid & 63, w = tid >> 6;
    int bx, by;
    xcd_swizzle(bx, by);
    int m0 = by * 128, n0 = bx * 128;
    int wm = (w >> 1) * 64, wn = (w & 1) * 64;
    int mi = lane & 15, quad = lane >> 4;
    int sw = mi & 7;                // read-side swizzle key

    f32x4 acc[4][4];
#pragma unroll
    for (int i = 0; i < 4; i++)
#pragma unroll
        for (int j = 0; j < 4; j++) acc[i][j] = (f32x4){0.f, 0.f, 0.f, 0.f};

    // staging geometry: round r covers rows r*32 + (tid>>3), 8x16B blocks/row
    int rr = tid >> 3;                              // 0..31
    int csrc = ((tid & 7) ^ (rr & 7)) * 8;          // swizzled source col (u16)
    int cdst = (tid & 7) * 8;                       // linear LDS col (u16)

    const u16* Asrc[4];
    u16* Adst[4];
#pragma unroll
    for (int r = 0; r < 4; r++) {
        Asrc[r] = A + (size_t)(m0 + r * 32 + rr) * K + csrc;
        Adst[r] = As + (r * 32 + rr) * 64 + cdst;
    }
    const u16* Bsrc[4];
    u16* Bdst[4];
#pragma unroll
    for (int r = 0; r < 4; r++) {
        Bsrc[r] = Bt + (size_t)(n0 + r * 32 + rr) * K + csrc;
        Bdst[r] = Bs + (r * 32 + rr) * 64 + cdst;
    }

    for (int kc = 0; kc < K; kc += 64) {
        __syncthreads();
#pragma unroll
        for (int r = 0; r < 4; r++) async16(Asrc[r] + kc, Adst[r]);
#pragma unroll
        for (int r = 0; r < 4; r++) async16(Bsrc[r] + kc, Bdst[r]);
        __syncthreads();

#pragma unroll
        for (int kk = 0; kk < 2; kk++) {
            int cb = ((kk * 4 + quad) ^ sw) * 8;    // swizzled read col
            bf16x8 af[4], bfr[4];
#pragma unroll
            for (int i = 0; i < 4; i++)
                af[i] = *(const bf16x8*)&As[(wm + i * 16 + mi) * 64 + cb];
#pragma unroll
            for (int j = 0; j < 4; j++)
                bfr[j] = *(const bf16x8*)&Bs[(wn + j * 16 + mi) * 64 + cb];
#pragma unroll
            for (int i = 0; i < 4; i++)
#pragma unroll
                for (int j = 0; j < 4; j++)
                    acc[i][j] = __builtin_amdgcn_mfma_f32_16x16x32_bf16(
                        af[i], bfr[j], acc[i][j], 0, 0, 0);
        }
    }

#pragma unroll
    for (int j = 0; j < 4; j++) {
        int col = n0 + wn + j * 16 + mi;
        int bi = col >> 9;
        const float* bp = (bi == 0) ? bias0 : (bi == 1) ? bias1
                        : (bi == 2) ? bias2 : bias3;
        float bb = bp[col & 511];
#pragma unroll
        for (int i = 0; i < 4; i++) {
#pragma unroll
            for (int r = 0; r < 4; r++) {
                int row = m0 + wm + i * 16 + quad * 4 + r;
                float o = acc[i][j][r] + bb;
                if (ACT) o = fmaxf(o, 0.f);
                if (OUT_F32) ((float*)Cv)[(size_t)row * N + col] = o;
                else         ((u16*)Cv)[(size_t)row * N + col] = f2b(o);
            }
        }
    }
}

// ---------------------------------------------------------------------------
// GEMM (narrow-N, N=512): 64x64 tile / 256 thr, BK=64, 2-phase dbuf + T1.
// grid 1024 blocks -> 4 blk/CU. Used for AO (K=512) and FF2 (K=2048) --
// R12 best routing. (R13 1-blk/CU wide, R14 128x64, R15 LN-fusion all
// neutral-or-worse; epilogue stays store-only.)
// ---------------------------------------------------------------------------
template <int ACT, bool OUT_F32>
__global__ __launch_bounds__(256) void gemm64_kernel(
    const u16* __restrict__ A, const u16* __restrict__ Bt,
    const float* __restrict__ bias0,
    void* __restrict__ Cv, int N, int K)
{
    __shared__ __align__(16) u16 As[2][64 * 64];
    __shared__ __align__(16) u16 Bs[2][64 * 64];

    int tid = threadIdx.x, lane = tid & 63, w = tid >> 6;
    int bx, by;
    xcd_swizzle(bx, by);
    int m0 = by * 64, n0 = bx * 64;
    int wm = (w >> 1) * 32, wn = (w & 1) * 32;
    int mi = lane & 15, quad = lane >> 4;
    int sw = mi & 7;

    f32x4 acc[2][2];
#pragma unroll
    for (int i = 0; i < 2; i++)
#pragma unroll
        for (int j = 0; j < 2; j++) acc[i][j] = (f32x4){0.f, 0.f, 0.f, 0.f};

    int rr = tid >> 3;                              // 0..31
    int csrc = ((tid & 7) ^ (rr & 7)) * 8;          // swizzled source col
    int cdst = (tid & 7) * 8;                       // linear LDS col

    const u16* Asrc[2];
    int Aoff[2];
#pragma unroll
    for (int r = 0; r < 2; r++) {
        Asrc[r] = A + (size_t)(m0 + r * 32 + rr) * K + csrc;
        Aoff[r] = (r * 32 + rr) * 64 + cdst;
    }
    const u16* Bsrc[2];
    int Boff[2];
#pragma unroll
    for (int r = 0; r < 2; r++) {
        Bsrc[r] = Bt + (size_t)(n0 + r * 32 + rr) * K + csrc;
        Boff[r] = (r * 32 + rr) * 64 + cdst;
    }

    // prologue: stage tile 0 into buffer 0
#pragma unroll
    for (int r = 0; r < 2; r++) async16(Asrc[r], &As[0][Aoff[r]]);
#pragma unroll
    for (int r = 0; r < 2; r++) async16(Bsrc[r], &Bs[0][Boff[r]]);
    __syncthreads();

    int cur = 0;
    for (int kc = 0; kc < K; kc += 64) {
        int nxt = kc + 64;
        if (nxt < K) {
#pragma unroll
            for (int r = 0; r < 2; r++) async16(Asrc[r] + nxt, &As[cur ^ 1][Aoff[r]]);
#pragma unroll
            for (int r = 0; r < 2; r++) async16(Bsrc[r] + nxt, &Bs[cur ^ 1][Boff[r]]);
        }

#pragma unroll
        for (int kk = 0; kk < 2; kk++) {
            int cb = ((kk * 4 + quad) ^ sw) * 8;
            bf16x8 af[2], bfr[2];
#pragma unroll
            for (int i = 0; i < 2; i++)
                af[i] = *(const bf16x8*)&As[cur][(wm + i * 16 + mi) * 64 + cb];
#pragma unroll
            for (int j = 0; j < 2; j++)
                bfr[j] = *(const bf16x8*)&Bs[cur][(wn + j * 16 + mi) * 64 + cb];
#pragma unroll
            for (int i = 0; i < 2; i++)
#pragma unroll
                for (int j = 0; j < 2; j++)
                    acc[i][j] = __builtin_amdgcn_mfma_f32_16x16x32_bf16(
                        af[i], bfr[j], acc[i][j], 0, 0, 0);
        }

        __syncthreads();        // drains next-tile loads; protects buf reuse
        cur ^= 1;
    }

#pragma unroll
    for (int j = 0; j < 2; j++) {
        int col = n0 + wn + j * 16 + mi;
        float bb = bias0[col & 511];
#pragma unroll
        for (int i = 0; i < 2; i++) {
#pragma unroll
            for (int r = 0; r < 4; r++) {
                int row = m0 + wm + i * 16 + quad * 4 + r;
                float o = acc[i][j][r] + bb;
                if (ACT) o = fmaxf(o, 0.f);
                if (OUT_F32) ((float*)Cv)[(size_t)row * N + col] = o;
                else         ((u16*)Cv)[(size_t)row * N + col] = f2b(o);
            }
        }
    }
}

// ---------------------------------------------------------------------------
// Flash attention (causal), fused-QKV input.  (R8 version, session-best.)
// ONE 64-row q-tile per block; 1024 blocks; CU-stack-balancing swizzle;
// two-deep K/V register prefetch. Swapped QK^T + in-register softmax +
// defer-rescale. R9-R11 established the structure is at its floor.
// ---------------------------------------------------------------------------
__global__ __launch_bounds__(256) void attn_kernel(
    const u16* __restrict__ qkv, u16* __restrict__ O)
{
    __shared__ __align__(16) u16 Kl[64][72];
    __shared__ __align__(16) u16 Vt[64][72];
    __shared__ __align__(16) u16 Pl[4][16][72];

    int tid = threadIdx.x, lane = tid & 63, w = tid >> 6;
    int id = blockIdx.x;          // 0..1023
    int u = id & 255, v = id >> 8;
    int p = u & 15;
    int qt = (v & 1) ? (31 - p) : p;
    int bh = (u >> 4) | ((v >> 1) << 4);
    int b = bh >> 3, h = bh & 7;
    int mi = lane & 15, quad = lane >> 4, k8 = quad * 8;

    size_t qbase = ((size_t)b * S_LEN) * QKV_STRIDE + h * 64;
    const u16* Qp = qkv + qbase;
    const u16* Kp = qkv + qbase + 512;
    const u16* Vp = qkv + qbase + 1024;
    size_t obase = ((size_t)b * S_LEN) * DM + h * 64;

    int srow = tid >> 2, sseg = tid & 3;
    int vcol = srow ^ (sseg * 8);

    f32x4 zero4 = {0.f, 0.f, 0.f, 0.f};
    const float SCL = 0.125f * 1.44269504089f;   // 1/sqrt(64) * log2(e)

    int q0 = qt * 64;

    // Q fragments (B-operand of the swapped QK^T): row = mi
    const u16* qrow = Qp + (size_t)(q0 + w * 16 + mi) * QKV_STRIDE;
    bf16x8 bq0 = *(const bf16x8*)(qrow + k8);
    bf16x8 bq1 = *(const bf16x8*)(qrow + 32 + k8);

    // two-deep prefetch: tiles 0 (a-regs) and 1 (b-regs). Tile-1 rows
    // 64..127 are always in-bounds; refills guarded by kt+2 <= qt.
    const u16* kr = Kp + (size_t)srow * QKV_STRIDE + sseg * 16;
    const u16* vr = Vp + (size_t)srow * QKV_STRIDE + sseg * 16;
    const size_t TSTR = (size_t)64 * QKV_STRIDE;
    u16x8 ka0 = *(const u16x8*)kr,          ka1 = *(const u16x8*)(kr + 8);
    u16x8 va0 = *(const u16x8*)vr,          va1 = *(const u16x8*)(vr + 8);
    u16x8 kb0 = *(const u16x8*)(kr + TSTR), kb1 = *(const u16x8*)(kr + TSTR + 8);
    u16x8 vb0 = *(const u16x8*)(vr + TSTR), vb1 = *(const u16x8*)(vr + TSTR + 8);

    // per-lane softmax state for q = w*16 + mi (replicated across quads)
    float mst = -__builtin_inff();
    float lst = 0.f;
    f32x4 acc[4];    // acc[g2][r] = O[q=quad*4+r][d=g2*16+mi]
#pragma unroll
    for (int g = 0; g < 4; g++) acc[g] = zero4;

    auto compute_tile = [&](int kt) {
        // QK^T (swapped): sc[g][r] = S[q = w*16+mi][k = g*16+quad*4+r] * SCL
        f32x4 sc[4];
#pragma unroll
        for (int g = 0; g < 4; g++) {
            bf16x8 a0 = *(const bf16x8*)&Kl[g * 16 + mi][k8];
            bf16x8 a1 = *(const bf16x8*)&Kl[g * 16 + mi][32 + k8];
            f32x4 s = __builtin_amdgcn_mfma_f32_16x16x32_bf16(a0, bq0, zero4, 0, 0, 0);
            s = __builtin_amdgcn_mfma_f32_16x16x32_bf16(a1, bq1, s, 0, 0, 0);
            sc[g] = s * SCL;
        }

        if (kt == qt) {   // causal mask on diagonal tile: k_local > q_local
            int qloc = w * 16 + mi;
#pragma unroll
            for (int g = 0; g < 4; g++) {
#pragma unroll
                for (int r = 0; r < 4; r++)
                    if (g * 16 + quad * 4 + r > qloc) sc[g][r] = -1e30f;
            }
        }

        // row max: in-register tree over 16 + 2-step cross-quad shfl
        f32x4 m4 = sc[0];
#pragma unroll
        for (int g = 1; g < 4; g++)
#pragma unroll
            for (int r = 0; r < 4; r++) m4[r] = fmaxf(m4[r], sc[g][r]);
        float rm = fmaxf(fmaxf(m4[0], m4[1]), fmaxf(m4[2], m4[3]));
        rm = fmaxf(rm, __shfl_xor(rm, 16));
        rm = fmaxf(rm, __shfl_xor(rm, 32));

        bool nore = __all(rm <= mst);        // wave-uniform: max didn't grow
        float mnew = fmaxf(mst, rm);

        float pr[4][4];
        f32x4 ps = zero4;
#pragma unroll
        for (int g = 0; g < 4; g++)
#pragma unroll
            for (int r = 0; r < 4; r++) {
                float p2 = exp2f(sc[g][r] - mnew);
                pr[g][r] = p2;
                ps[r] += p2;
            }
        float rs = (ps[0] + ps[1]) + (ps[2] + ps[3]);
        rs += __shfl_xor(rs, 16);
        rs += __shfl_xor(rs, 32);

        if (!nore) {
            float alpha = exp2f(mst - mnew);
            mst = mnew;
            lst *= alpha;
            // redistribute alpha to acc rows (q-local = quad*4+r)
            float aR[4];
#pragma unroll
            for (int r = 0; r < 4; r++) aR[r] = __shfl(alpha, quad * 4 + r);
#pragma unroll
            for (int g2 = 0; g2 < 4; g2++)
#pragma unroll
                for (int r = 0; r < 4; r++) acc[g2][r] *= aR[r];
        }
        lst += rs;

        // P -> LDS (wave-private): row = q = mi, cols g*16+quad*4..+3
#pragma unroll
        for (int g = 0; g < 4; g++) {
            u16x4 pk;
#pragma unroll
            for (int r = 0; r < 4; r++) pk[r] = f2b(pr[g][r]);
            *(u16x4*)&Pl[w][mi][g * 16 + quad * 4] = pk;
        }

        // PV (Vt read with un-swizzle)
#pragma unroll
        for (int kc2 = 0; kc2 < 2; kc2++) {
            bf16x8 ap = *(const bf16x8*)&Pl[w][mi][kc2 * 32 + k8];
#pragma unroll
            for (int g2 = 0; g2 < 4; g2++) {
                bf16x8 bv = *(const bf16x8*)&Vt[g2 * 16 + mi][kc2 * 32 + ((quad ^ g2) * 8)];
                acc[g2] = __builtin_amdgcn_mfma_f32_16x16x32_bf16(ap, bv, acc[g2], 0, 0, 0);
            }
        }
    };

#define ATTN_STEP(KT, K0, K1, V0, V1)                                        \
    {                                                                        \
        const int kt_ = (KT);                                                \
        __syncthreads();                                                     \
        *(u16x8*)&Kl[srow][sseg * 16] = K0;                                  \
        *(u16x8*)&Kl[srow][sseg * 16 + 8] = K1;                              \
        _Pragma("unroll")                                                    \
        for (int j = 0; j < 8; j++) {                                        \
            Vt[sseg * 16 + j][vcol] = V0[j];                                 \
            Vt[sseg * 16 + 8 + j][vcol] = V1[j];                             \
        }                                                                    \
        __syncthreads();                                                     \
        if (kt_ + 2 <= qt) {                                                 \
            const u16* krn = kr + (size_t)(kt_ + 2) * TSTR;                  \
            const u16* vrn = vr + (size_t)(kt_ + 2) * TSTR;                  \
            K0 = *(const u16x8*)krn; K1 = *(const u16x8*)(krn + 8);          \
            V0 = *(const u16x8*)vrn; V1 = *(const u16x8*)(vrn + 8);          \
        }                                                                    \
        compute_tile(kt_);                                                   \
    }

    for (int kt = 0; kt <= qt; kt += 2) {
        ATTN_STEP(kt, ka0, ka1, va0, va1);
        if (kt + 1 <= qt) ATTN_STEP(kt + 1, kb0, kb1, vb0, vb1);
    }
#undef ATTN_STEP

    // epilogue: pull l for acc rows (q-local = quad*4+r) via shfl
    float invL[4];
#pragma unroll
    for (int r = 0; r < 4; r++) invL[r] = 1.f / __shfl(lst, quad * 4 + r);
#pragma unroll
    for (int g2 = 0; g2 < 4; g2++)
#pragma unroll
        for (int r = 0; r < 4; r++) {
            float o = acc[g2][r] * invL[r];
            O[obase + (size_t)(q0 + w * 16 + quad * 4 + r) * DM + g2 * 16 + mi] = f2b(o);
        }
}

// ---------------------------------------------------------------------------
// x = LN(x + delta); writes fp32 master + bf16 shadow. One wave per row,
// float4-vectorized (lane owns 8 contiguous elements; mean/var are
// order-independent so the remap is exact). Two-input form (R15's fused
// variant regressed; epilogue-coupled residual reads cost more than the
// saved LN read).
// ---------------------------------------------------------------------------
__global__ __launch_bounds__(256) void add_ln_kernel(
    const float* __restrict__ X, const float* __restrict__ Dl,
    const float* __restrict__ G, const float* __restrict__ Bb,
    float* __restrict__ Xout, u16* __restrict__ Bout)
{
    int tid = threadIdx.x, lane = tid & 63, w = tid >> 6;
    int row = blockIdx.x * 4 + w;
    size_t off = (size_t)row * DM + lane * 8;

    float4 x0 = *(const float4*)&X[off];
    float4 x1 = *(const float4*)&X[off + 4];
    float4 d0 = *(const float4*)&Dl[off];
    float4 d1 = *(const float4*)&Dl[off + 4];
    float v[8] = {x0.x + d0.x, x0.y + d0.y, x0.z + d0.z, x0.w + d0.w,
                  x1.x + d1.x, x1.y + d1.y, x1.z + d1.z, x1.w + d1.w};

    float s = 0.f;
#pragma unroll
    for (int j = 0; j < 8; j++) s += v[j];
#pragma unroll
    for (int d = 1; d < 64; d <<= 1) s += __shfl_xor(s, d);
    float mean = s * (1.f / 512.f);
    float vs = 0.f;
#pragma unroll
    for (int j = 0; j < 8; j++) { float t = v[j] - mean; vs += t * t; }
#pragma unroll
    for (int d = 1; d < 64; d <<= 1) vs += __shfl_xor(vs, d);
    float rstd = rsqrtf(vs * (1.f / 512.f) + 1e-5f);

    float4 g0 = *(const float4*)&G[lane * 8];
    float4 g1 = *(const float4*)&G[lane * 8 + 4];
    float4 b0 = *(const float4*)&Bb[lane * 8];
    float4 b1 = *(const float4*)&Bb[lane * 8 + 4];
    float gg[8] = {g0.x, g0.y, g0.z, g0.w, g1.x, g1.y, g1.z, g1.w};
    float bb[8] = {b0.x, b0.y, b0.z, b0.w, b1.x, b1.y, b1.z, b1.w};

    float o[8];
    u16x8 ob;
#pragma unroll
    for (int j = 0; j < 8; j++) {
        o[j] = (v[j] - mean) * rstd * gg[j] + bb[j];
        ob[j] = f2b(o[j]);
    }
    *(float4*)&Xout[off]     = (float4){o[0], o[1], o[2], o[3]};
    *(float4*)&Xout[off + 4] = (float4){o[4], o[5], o[6], o[7]};
    *(u16x8*)&Bout[off] = ob;
}

// ---------------------------------------------------------------------------
extern "C" void kernel_launch(void* const* d_in, const int* in_sizes, int n_in,
                              void* d_out, int out_size, void* d_ws, size_t ws_size,
                              hipStream_t stream)
{
    const int*   src  = (const int*)d_in[0];
    const float* emb  = (const float*)d_in[1];
    const float* ln_g = (const float*)d_in[2];
    const float* ln_b = (const float*)d_in[3];
    const float* wq = (const float*)d_in[4];
    const float* bq = (const float*)d_in[5];
    const float* wk = (const float*)d_in[6];
    const float* bk = (const float*)d_in[7];
    const float* wv = (const float*)d_in[8];
    const float* bv = (const float*)d_in[9];
    const float* wo = (const float*)d_in[10];
    const float* bo = (const float*)d_in[11];
    const float* w1 = (const float*)d_in[12];
    const float* b1 = (const float*)d_in[13];
    const float* w2 = (const float*)d_in[14];
    const float* b2 = (const float*)d_in[15];

    char* ws = (char*)d_ws;
    float* xf  = (float*)(ws);
    u16*   xb  = (u16*)(ws + (16u << 20));
    u16*   qkv = (u16*)(ws + (24u << 20));
    u16*   ab  = (u16*)(ws + (48u << 20));
    u16*   h1  = (u16*)(ws + (24u << 20));   // aliases qkv+ab
    float* dlt = (float*)(ws + (56u << 20));
    u16*   wbf = (u16*)(ws + (72u << 20));

    u16* qkvt = wbf;                              // [L][1536][512]
    u16* wot  = wbf + 6u * 1536 * 512;            // [L][512][512]
    u16* w1t  = wot + 6u * 512 * 512;             // [L][2048][512]
    u16* w2t  = w1t + 6u * 512 * 2048;            // [L][512][2048]

    const int ROWS = 4 * S_LEN;   // 8192

    transp_kernel<<<dim3(8, 8, 6),  256, 0, stream>>>(wq, qkvt, 512, 512, 1536u * 512, 0);
    transp_kernel<<<dim3(8, 8, 6),  256, 0, stream>>>(wk, qkvt, 512, 512, 1536u * 512, 512);
    transp_kernel<<<dim3(8, 8, 6),  256, 0, stream>>>(wv, qkvt, 512, 512, 1536u * 512, 1024);
    transp_kernel<<<dim3(8, 8, 6),  256, 0, stream>>>(wo, wot, 512, 512, 512u * 512, 0);
    transp_kernel<<<dim3(32, 8, 6), 256, 0, stream>>>(w1, w1t, 512, 2048, 2048u * 512, 0);
    transp_kernel<<<dim3(8, 32, 6), 256, 0, stream>>>(w2, w2t, 2048, 512, 512u * 2048, 0);

    embed_kernel<<<ROWS / 4, 256, 0, stream>>>(src, emb, xf, xb);

    dim3 gqkv(1536 / 128, ROWS / 128);   // 768 blocks (div by 8)
    dim3 g64(512 / 64, ROWS / 64);       // 1024 blocks (div by 8)
    dim3 g2048(2048 / 128, ROWS / 128);  // 1024 blocks (div by 8)

    for (int l = 0; l < 6; l++) {
        const u16* Wqkv = qkvt + (size_t)l * 1536 * 512;
        const u16* Wo   = wot + (size_t)l * 512 * 512;
        const u16* W1   = w1t + (size_t)l * 2048 * 512;
        const u16* W2   = w2t + (size_t)l * 512 * 2048;
        const float* Bq = bq + l * DM;
        const float* Bk = bk + l * DM;
        const float* Bv = bv + l * DM;
        const float* Bo = bo + l * DM;
        const float* B1 = b1 + l * FF;
        const float* B2 = b2 + l * DM;

        gemm_kernel<0, false><<<gqkv, 256, 0, stream>>>(
            xb, Wqkv, Bq, Bk, Bv, Bv, qkv, QKV_STRIDE, 512);

        attn_kernel<<<1024, 256, 0, stream>>>(qkv, ab);

        gemm64_kernel<0, true><<<g64, 256, 0, stream>>>(
            ab, Wo, Bo, dlt, 512, 512);
        add_ln_kernel<<<ROWS / 4, 256, 0, stream>>>(xf, dlt, ln_g, ln_b, xf, xb);

        gemm_kernel<1, false><<<g2048, 256, 0, stream>>>(
            xb, W1, B1, B1 + 512, B1 + 1024, B1 + 1536, h1, FF, 512);
        gemm64_kernel<1, true><<<g64, 256, 0, stream>>>(
            h1, W2, B2, dlt, 512, 2048);
        add_ln_kernel<<<ROWS / 4, 256, 0, stream>>>(xf, dlt, ln_g, ln_b,
                                                    (l == 5) ? (float*)d_out : xf, xb);
    }
}